// Round 4
// baseline (404.131 us; speedup 1.0000x reference)
//
#include <hip/hip_runtime.h>
#include <math.h>

#define N_ROWS 131072
#define DIMS 64
#define K_CODES 512
#define ARG_BLOCKS (N_ROWS / 256)  // 512 blocks, 1 row per thread

// ---------------- K0: zero bins + c2 via numpy-pairwise (bitwise) --------
__global__ __launch_bounds__(256) void vq_init(const float* __restrict__ codebook,
                                               int* __restrict__ bins,
                                               float* __restrict__ c2g) {
  #pragma clang fp contract(off)
  const int t = threadIdx.x;
  for (int b = t; b < K_CODES; b += 256) bins[b] = 0;
  // numpy pairwise_sum, n=64: 8 accumulators over stride-8 lanes, then fixed tree.
  for (int k = t; k < K_CODES; k += 256) {
    const float* cr = codebook + k * DIMS;
    float r[8];
    #pragma unroll
    for (int j = 0; j < 8; ++j) r[j] = cr[j] * cr[j];
    for (int i = 8; i < 64; i += 8) {
      #pragma unroll
      for (int j = 0; j < 8; ++j) r[j] += cr[i + j] * cr[i + j];  // contract OFF: mul, then add
    }
    c2g[k] = ((r[0] + r[1]) + (r[2] + r[3])) + ((r[4] + r[5]) + (r[6] + r[7]));
  }
}

// ---------------- K1: fused argmin + outputs. NO LDS in the GEMM. ----------------
// 1 row per lane, x[64] held in VGPRs for the whole kernel. All lanes sweep the
// same codes, so codebook/c2 loads have wave-uniform indices -> s_load into SGPRs;
// v_fmac_f32 takes the code value as its one scalar operand. Zero LDS traffic,
// zero bank conflicts, no staging barriers.
// Numerics (bitwise np): M = sequential fmaf over ascending d; d2 = (x2 - 2M) + c2;
// strict < with ascending k == np first-index argmin.
__global__ __launch_bounds__(256, 2) void vq_argmin(const float* __restrict__ latents,
                                                    const float* __restrict__ codebook,
                                                    const float* __restrict__ c2g,
                                                    float* __restrict__ out_codes,
                                                    int* __restrict__ bins,
                                                    float* __restrict__ out_st,
                                                    double* __restrict__ loss_part) {
  #pragma clang fp contract(off)
  const int t = threadIdx.x;
  const int row = blockIdx.x * 256 + t;

  // x row -> registers (16 dwordx4); all later indices are unroll-constant.
  float xf[64];
  {
    const float4* xr = (const float4*)(latents + (size_t)row * DIMS);
    #pragma unroll
    for (int p = 0; p < 16; ++p) *(float4*)&xf[p * 4] = xr[p];
  }

  // x2: numpy pairwise (n=64), fully per-lane. a_d = fl(x_d^2), stride-8 chains, tree.
  float x2;
  {
    float r[8];
    #pragma unroll
    for (int j = 0; j < 8; ++j) { const float v = xf[j]; r[j] = v * v; }
    #pragma unroll
    for (int i = 8; i < 64; i += 8) {
      #pragma unroll
      for (int j = 0; j < 8; ++j) { const float v = xf[i + j]; r[j] += v * v; }
    }
    x2 = ((r[0] + r[1]) + (r[2] + r[3])) + ((r[4] + r[5]) + (r[6] + r[7]));
  }

  float m1 = __builtin_inff();
  int i1 = 0x7fffffff;
  const float4* cb4 = (const float4*)codebook;

  for (int k0 = 0; k0 < K_CODES; k0 += 8) {
    float acc[8];
    #pragma unroll
    for (int j = 0; j < 8; ++j) acc[j] = 0.f;

    #pragma unroll
    for (int d4 = 0; d4 < 16; ++d4) {
      float4 cj[8];
      #pragma unroll
      for (int j = 0; j < 8; ++j) cj[j] = cb4[(k0 + j) * 16 + d4];  // uniform -> s_load
      #pragma unroll
      for (int j = 0; j < 8; ++j) {  // d strictly ascending per acc chain
        acc[j] = fmaf(xf[d4 * 4 + 0], cj[j].x, acc[j]);
        acc[j] = fmaf(xf[d4 * 4 + 1], cj[j].y, acc[j]);
        acc[j] = fmaf(xf[d4 * 4 + 2], cj[j].z, acc[j]);
        acc[j] = fmaf(xf[d4 * 4 + 3], cj[j].w, acc[j]);
      }
    }

    #pragma unroll
    for (int j = 0; j < 8; ++j) {
      const float c2v = c2g[k0 + j];              // uniform -> s_load
      const float s = (x2 - 2.0f * acc[j]) + c2v; // two rounded fp32 ops (2*acc exact)
      if (s < m1) { m1 = s; i1 = k0 + j; }        // strict <, k ascending: first index
    }
  }

  out_codes[row] = (float)i1;   // coalesced
  atomicAdd(&bins[i1], 1);

  // fused outputs: gather q (codebook hot in L1/L2), STE write, fp64 loss partial.
  double dacc = 0.0;
  {
    const float4* q4 = cb4 + (size_t)i1 * 16;
    float4* o4 = (float4*)(out_st + (size_t)row * DIMS);
    #pragma unroll
    for (int p = 0; p < 16; ++p) {
      const float4 q = q4[p];
      const float4 l = *(const float4*)&xf[p * 4];
      float4 o;
      o.x = l.x + (q.x - l.x);  // straight-through, np rounding order
      o.y = l.y + (q.y - l.y);
      o.z = l.z + (q.z - l.z);
      o.w = l.w + (q.w - l.w);
      o4[p] = o;
      const float dx = l.x - q.x, dy = l.y - q.y, dz = l.z - q.z, dw = l.w - q.w;
      dacc += (double)dx * (double)dx;
      dacc += (double)dy * (double)dy;
      dacc += (double)dz * (double)dz;
      dacc += (double)dw * (double)dw;
    }
  }
  #pragma unroll
  for (int off = 32; off > 0; off >>= 1) dacc += __shfl_down(dacc, off);
  __shared__ double wsum[4];
  if ((t & 63) == 0) wsum[t >> 6] = dacc;
  __syncthreads();
  if (t == 0) loss_part[blockIdx.x] = wsum[0] + wsum[1] + wsum[2] + wsum[3];
}

// ---------------- K2: reduce loss partials + perplexity + scalar outputs ----------
__global__ __launch_bounds__(512) void vq_finalize(const int* __restrict__ bins,
                                                   const double* __restrict__ loss_part,
                                                   float* __restrict__ out3) {
  __shared__ double red[512];
  __shared__ double redl[512];
  const int t = threadIdx.x;
  const double p = (double)bins[t] / 131072.0;
  red[t] = -p * log(p + 1e-10);
  redl[t] = loss_part[t];
  __syncthreads();
  for (int s = 256; s > 0; s >>= 1) {
    if (t < s) { red[t] += red[t + s]; redl[t] += redl[t + s]; }
    __syncthreads();
  }
  if (t == 0) {
    const double mean = redl[0] / 8388608.0;
    out3[0] = (float)(0.25 * mean);  // commitment * COMMITMENT_COST
    out3[1] = (float)mean;           // codebook_loss (same squares bitwise)
    out3[2] = (float)exp(red[0]);    // perplexity
  }
}

extern "C" void kernel_launch(void* const* d_in, const int* in_sizes, int n_in,
                              void* d_out, int out_size, void* d_ws, size_t ws_size,
                              hipStream_t stream) {
  const float* latents = (const float*)d_in[0];
  const float* codebook = (const float*)d_in[1];

  float* out = (float*)d_out;
  float* out_st = out;                                   // 8388608
  float* out_codes = out + (size_t)N_ROWS * DIMS;        // 131072 (codes as float)
  float* out3 = out_codes + N_ROWS;                      // 3 scalars

  char* ws = (char*)d_ws;
  double* loss_part = (double*)ws;               // [0, 4096)   512 slots
  int* bins = (int*)(ws + 4096);                 // [4096, 6144)
  float* c2g = (float*)(ws + 6144);              // [6144, 8192)

  hipLaunchKernelGGL(vq_init, dim3(1), dim3(256), 0, stream,
                     codebook, bins, c2g);
  hipLaunchKernelGGL(vq_argmin, dim3(ARG_BLOCKS), dim3(256), 0, stream,
                     latents, codebook, c2g, out_codes, bins, out_st, loss_part);
  hipLaunchKernelGGL(vq_finalize, dim3(1), dim3(512), 0, stream,
                     bins, loss_part, out3);
}

// Round 5
// 400.801 us; speedup vs baseline: 1.0083x; 1.0083x over previous
//
#include <hip/hip_runtime.h>
#include <math.h>

#define N_ROWS 131072
#define DIMS 64
#define K_CODES 512
#define ARG_BLOCKS (N_ROWS / 256)  // 512 blocks, 1 row per thread

// ---------------- K0: zero bins + c2 via numpy-pairwise (bitwise) --------
__global__ __launch_bounds__(256) void vq_init(const float* __restrict__ codebook,
                                               int* __restrict__ bins,
                                               float* __restrict__ c2g) {
  #pragma clang fp contract(off)
  const int t = threadIdx.x;
  for (int b = t; b < K_CODES; b += 256) bins[b] = 0;
  // numpy pairwise_sum, n=64: 8 accumulators over stride-8 lanes, then fixed tree.
  for (int k = t; k < K_CODES; k += 256) {
    const float* cr = codebook + k * DIMS;
    float r[8];
    #pragma unroll
    for (int j = 0; j < 8; ++j) r[j] = cr[j] * cr[j];
    for (int i = 8; i < 64; i += 8) {
      #pragma unroll
      for (int j = 0; j < 8; ++j) r[j] += cr[i + j] * cr[i + j];  // contract OFF: mul, then add
    }
    c2g[k] = ((r[0] + r[1]) + (r[2] + r[3])) + ((r[4] + r[5]) + (r[6] + r[7]));
  }
}

// ---------------- K1: fused argmin + outputs. NO LDS in the GEMM. ----------------
// 1 row per lane, x[64] in VGPRs (SROA-friendly: address of xf is NEVER taken —
// float4 loads land in values, components assigned with constant indices).
// All lanes sweep the same codes -> codebook/c2 loads are wave-uniform -> s_load.
// Numerics (bitwise np): M = sequential fmaf over ascending d; d2 = (x2 - 2M) + c2;
// strict < with ascending k == np first-index argmin.
__global__ __launch_bounds__(256, 2) void vq_argmin(const float* __restrict__ latents,
                                                    const float* __restrict__ codebook,
                                                    const float* __restrict__ c2g,
                                                    float* __restrict__ out_codes,
                                                    int* __restrict__ bins,
                                                    float* __restrict__ out_st,
                                                    double* __restrict__ loss_part) {
  #pragma clang fp contract(off)
  const int t = threadIdx.x;
  const int row = blockIdx.x * 256 + t;

  // x row -> registers. No address-taken on xf: component-wise assigns only.
  float xf[64];
  {
    const float4* xr = (const float4*)(latents + (size_t)row * DIMS);
    #pragma unroll
    for (int p = 0; p < 16; ++p) {
      const float4 v = xr[p];
      xf[4 * p + 0] = v.x;
      xf[4 * p + 1] = v.y;
      xf[4 * p + 2] = v.z;
      xf[4 * p + 3] = v.w;
    }
  }

  // x2: numpy pairwise (n=64), per-lane. a_d = fl(x_d^2), stride-8 chains, tree.
  float x2;
  {
    float r[8];
    #pragma unroll
    for (int j = 0; j < 8; ++j) { const float v = xf[j]; r[j] = v * v; }
    #pragma unroll
    for (int i = 8; i < 64; i += 8) {
      #pragma unroll
      for (int j = 0; j < 8; ++j) { const float v = xf[i + j]; r[j] += v * v; }
    }
    x2 = ((r[0] + r[1]) + (r[2] + r[3])) + ((r[4] + r[5]) + (r[6] + r[7]));
  }

  float m1 = __builtin_inff();
  int i1 = 0x7fffffff;
  const float4* cb4 = (const float4*)codebook;

  for (int k0 = 0; k0 < K_CODES; k0 += 8) {
    float acc[8];
    #pragma unroll
    for (int j = 0; j < 8; ++j) acc[j] = 0.f;

    #pragma unroll
    for (int d4 = 0; d4 < 16; ++d4) {
      #pragma unroll
      for (int j = 0; j < 8; ++j) {
        const float4 c = cb4[(k0 + j) * 16 + d4];  // wave-uniform -> s_load_dwordx4
        // d strictly ascending per acc chain (bitwise sgemm order)
        acc[j] = fmaf(xf[4 * d4 + 0], c.x, acc[j]);
        acc[j] = fmaf(xf[4 * d4 + 1], c.y, acc[j]);
        acc[j] = fmaf(xf[4 * d4 + 2], c.z, acc[j]);
        acc[j] = fmaf(xf[4 * d4 + 3], c.w, acc[j]);
      }
    }

    #pragma unroll
    for (int j = 0; j < 8; ++j) {
      const float c2v = c2g[k0 + j];              // wave-uniform -> s_load
      const float s = (x2 - 2.0f * acc[j]) + c2v; // two rounded fp32 ops (2*acc exact)
      if (s < m1) { m1 = s; i1 = k0 + j; }        // strict <, k ascending: first index
    }
  }

  out_codes[row] = (float)i1;   // coalesced
  atomicAdd(&bins[i1], 1);

  // fused outputs: gather q (codebook L1/L2-hot), STE write, fp64 loss partial.
  double dacc = 0.0;
  {
    const float4* q4 = cb4 + (size_t)i1 * 16;
    float4* o4 = (float4*)(out_st + (size_t)row * DIMS);
    #pragma unroll
    for (int p = 0; p < 16; ++p) {
      const float4 q = q4[p];
      const float lx = xf[4 * p + 0], ly = xf[4 * p + 1];
      const float lz = xf[4 * p + 2], lw = xf[4 * p + 3];
      float4 o;
      o.x = lx + (q.x - lx);  // straight-through, np rounding order
      o.y = ly + (q.y - ly);
      o.z = lz + (q.z - lz);
      o.w = lw + (q.w - lw);
      o4[p] = o;
      const float dx = lx - q.x, dy = ly - q.y, dz = lz - q.z, dw = lw - q.w;
      dacc += (double)dx * (double)dx;
      dacc += (double)dy * (double)dy;
      dacc += (double)dz * (double)dz;
      dacc += (double)dw * (double)dw;
    }
  }
  #pragma unroll
  for (int off = 32; off > 0; off >>= 1) dacc += __shfl_down(dacc, off);
  __shared__ double wsum[4];
  if ((t & 63) == 0) wsum[t >> 6] = dacc;
  __syncthreads();
  if (t == 0) loss_part[blockIdx.x] = wsum[0] + wsum[1] + wsum[2] + wsum[3];
}

// ---------------- K2: reduce loss partials + perplexity + scalar outputs ----------
__global__ __launch_bounds__(512) void vq_finalize(const int* __restrict__ bins,
                                                   const double* __restrict__ loss_part,
                                                   float* __restrict__ out3) {
  __shared__ double red[512];
  __shared__ double redl[512];
  const int t = threadIdx.x;
  const double p = (double)bins[t] / 131072.0;
  red[t] = -p * log(p + 1e-10);
  redl[t] = loss_part[t];
  __syncthreads();
  for (int s = 256; s > 0; s >>= 1) {
    if (t < s) { red[t] += red[t + s]; redl[t] += redl[t + s]; }
    __syncthreads();
  }
  if (t == 0) {
    const double mean = redl[0] / 8388608.0;
    out3[0] = (float)(0.25 * mean);  // commitment * COMMITMENT_COST
    out3[1] = (float)mean;           // codebook_loss (same squares bitwise)
    out3[2] = (float)exp(red[0]);    // perplexity
  }
}

extern "C" void kernel_launch(void* const* d_in, const int* in_sizes, int n_in,
                              void* d_out, int out_size, void* d_ws, size_t ws_size,
                              hipStream_t stream) {
  const float* latents = (const float*)d_in[0];
  const float* codebook = (const float*)d_in[1];

  float* out = (float*)d_out;
  float* out_st = out;                                   // 8388608
  float* out_codes = out + (size_t)N_ROWS * DIMS;        // 131072 (codes as float)
  float* out3 = out_codes + N_ROWS;                      // 3 scalars

  char* ws = (char*)d_ws;
  double* loss_part = (double*)ws;               // [0, 4096)   512 slots
  int* bins = (int*)(ws + 4096);                 // [4096, 6144)
  float* c2g = (float*)(ws + 6144);              // [6144, 8192)

  hipLaunchKernelGGL(vq_init, dim3(1), dim3(256), 0, stream,
                     codebook, bins, c2g);
  hipLaunchKernelGGL(vq_argmin, dim3(ARG_BLOCKS), dim3(256), 0, stream,
                     latents, codebook, c2g, out_codes, bins, out_st, loss_part);
  hipLaunchKernelGGL(vq_finalize, dim3(1), dim3(512), 0, stream,
                     bins, loss_part, out3);
}